// Round 10
// baseline (1945.757 us; speedup 1.0000x reference)
//
#include <hip/hip_runtime.h>

// EncoderLSTM: T=512 steps, B=256, Din=33 (y:32 + t:1), H=512, OUT=32.
// Persistent cooperative kernel: 128 WGs x 512 thr = 8 batch-groups (32 rows) x 16 unit-groups
// (32 units). Per step per WG: gates[32x128] = [h|x|0] @ Wext^T, 36 MFMA/wave (8 waves).
// Sync protocol EXACTLY R6 (1603us proven): wave0 polls cohort flags (now 16) w/ s_sleep(1),
// barrier; publish h via agent atomics; __syncthreads drain; tid0 single flag store.
// W staged to LDS in TWO 64-row phases (region reused), B-frags -> registers per wave.

#define T_STEPS 512
#define BATCH   256
#define HID     512
#define RSTRIDE 1168                  // LDS row stride bytes (292 banks % 32 = 4)
#define GSTRIDE 1024                  // global h-image row stride bytes (512 units * 2B)
#define HOFF    (64 * RSTRIDE)        // staging region: 64 rows -> 74752 B
#define LDS_BYTES (96 * RSTRIDE)      // + h tile 32 rows -> 112128 B
#define IMG_HALF (BATCH * HID)        // u16 elements per h buffer (262144 B)

typedef __attribute__((ext_vector_type(8))) short short8; // 8 bf16 (4 VGPRs)
typedef __attribute__((ext_vector_type(4))) float f32x4;

__device__ __forceinline__ unsigned short f2bf(float f) { // RNE
  union { float f; unsigned u; } v; v.f = f;
  unsigned r = v.u + 0x7FFFu + ((v.u >> 16) & 1u);
  return (unsigned short)(r >> 16);
}
__device__ __forceinline__ float sigm(float x) { return 1.f / (1.f + __expf(-x)); }
__device__ __forceinline__ float tanh_f(float x) { return 1.f - 2.f / (__expf(2.f * x) + 1.f); }

__global__ void __launch_bounds__(512, 1)
lstm_persist(const float* __restrict__ y, const float* __restrict__ tin,
             const float* __restrict__ Wih, const float* __restrict__ Whh,
             const float* __restrict__ bih, const float* __restrict__ bhh,
             unsigned short* __restrict__ img,   // [2][256][512] bf16 h
             float* __restrict__ hf32,           // [256][512]
             int* __restrict__ flags)            // [128][16] (64B stride)
{
  __shared__ __align__(16) unsigned char sm[LDS_BYTES];
  const int tid  = threadIdx.x;
  const int wave = tid >> 6, lane = tid & 63;
  const int bid  = blockIdx.x;
  const int wg_m = bid & 7;            // batch-group (8)
  const int m0   = wg_m << 5;          // batch base (32 rows)
  const int u0   = (bid >> 3) << 5;    // unit base (32 units -> 128 gate-cols)

  // per-lane geometry (R6-verified, cl extended to 0..127 across 8 waves)
  const int cl   = (wave << 4) + (lane & 15);            // local gate-col 0..127
  const int rg_l = ((cl & 3) << 9) + u0 + (cl >> 2);
  const int ug   = u0 + (cl >> 2);                       // global unit of this lane
  const int g    = lane & 3;
  const int arow = lane & 15;
  const int kbyl = (lane >> 4) << 4;
  const int rowbase = ((g >> 1) << 4) + ((lane >> 4) << 2) + ((g & 1) << 1);
  const float bias = bih[rg_l] + bhh[rg_l];
  float c0 = 0.f, c1 = 0.f;
  int* const own_flag = flags + bid * 16;
  const int grow = tid >> 4, gq = tid & 15;              // gather: 32 rows x 16 thr x 8 u64

  // ---- stage W_ext in two 64-row phases; extract B-frags to registers ----
  short8 bfr[18];
  #pragma unroll
  for (int hh = 0; hh < 2; ++hh) {
    {
      const int c2 = tid >> 3, part = tid & 7;          // 64 rows x 8 parts x 64 elems
      const int c  = (hh << 6) + c2;                    // local W row 0..127
      const int rg = ((c & 3) << 9) + u0 + (c >> 2);    // global gate-row
      const float* whrow = Whh + (size_t)rg * HID;
      const int k0 = part << 6;
      const float4* src = (const float4*)(whrow + k0);
      #pragma unroll
      for (int i = 0; i < 16; ++i) {
        float4 f = src[i];
        uint2 p2;
        p2.x = (unsigned)f2bf(f.x) | ((unsigned)f2bf(f.y) << 16);
        p2.y = (unsigned)f2bf(f.z) | ((unsigned)f2bf(f.w) << 16);
        *(uint2*)&sm[c2 * RSTRIDE + ((k0 + i * 4) << 1)] = p2;
      }
      if (part == 7) {
        const float* wirow = Wih + (size_t)rg * 33;     // x weights: elems 512..543
        for (int d = 0; d < 32; d += 2) {
          unsigned p = (unsigned)f2bf(wirow[d]) | ((unsigned)f2bf(wirow[d + 1]) << 16);
          *(unsigned*)&sm[c2 * RSTRIDE + 1024 + (d << 1)] = p;
        }
        *(unsigned short*)&sm[c2 * RSTRIDE + 1088] = f2bf(wirow[32]);  // t weight
        *(unsigned short*)&sm[c2 * RSTRIDE + 1090] = 0;
        *(unsigned*)&sm[c2 * RSTRIDE + 1092] = 0;
        uint4 z; z.x = z.y = z.z = z.w = 0;
        *(uint4*)&sm[c2 * RSTRIDE + 1096] = z;
        *(uint4*)&sm[c2 * RSTRIDE + 1112] = z;
        *(uint4*)&sm[c2 * RSTRIDE + 1128] = z;
        *(uint4*)&sm[c2 * RSTRIDE + 1144] = z;
      }
    }
    __syncthreads();
    if ((wave >> 2) == hh) {
      #pragma unroll
      for (int ks = 0; ks < 18; ++ks)
        bfr[ks] = *(const short8*)&sm[(cl & 63) * RSTRIDE + (ks << 6) + kbyl];
    }
    __syncthreads();
  }
  // zero h-tile K-pad (bytes 1104..1151; 1088..1103 rewritten each step) — once
  if (tid < 128) {
    int row = tid >> 2, i = tid & 3;
    if (i < 3) {
      uint4 z; z.x = z.y = z.z = z.w = 0;
      *(uint4*)&sm[HOFF + row * RSTRIDE + 1104 + i * 16] = z;
    }
  }

  // ---- x prefetch for step 0 ----
  float4 xf0 = {0,0,0,0}, xf1 = {0,0,0,0}; float tpf = 0.f;
  if (tid < 128) {
    const int row = tid >> 2, part = tid & 3;
    const float* ysrc = y + (((size_t)(T_STEPS - 1) * BATCH + m0 + row) << 5) + (part << 3);
    xf0 = ((const float4*)ysrc)[0];
    xf1 = ((const float4*)ysrc)[1];
    if (part == 3) tpf = tin[(size_t)(T_STEPS - 1) * BATCH + m0 + row];
  }
  __syncthreads();

  for (int s = 0; s < T_STEPS; ++s) {
    // ---- [A] x tile from prefetch regs -> LDS (elems 512..544) ----
    if (tid < 128) {
      const int row = tid >> 2, part = tid & 3;
      uint4 p;
      p.x = (unsigned)f2bf(xf0.x) | ((unsigned)f2bf(xf0.y) << 16);
      p.y = (unsigned)f2bf(xf0.z) | ((unsigned)f2bf(xf0.w) << 16);
      p.z = (unsigned)f2bf(xf1.x) | ((unsigned)f2bf(xf1.y) << 16);
      p.w = (unsigned)f2bf(xf1.z) | ((unsigned)f2bf(xf1.w) << 16);
      *(uint4*)&sm[HOFF + row * RSTRIDE + 1024 + (part << 4)] = p;
      if (part == 3) {
        uint4 tz; tz.x = (unsigned)f2bf(tpf); tz.y = tz.z = tz.w = 0;
        *(uint4*)&sm[HOFF + row * RSTRIDE + 1088] = tz;   // t + zeros (elems 544..551)
      }
    }
    // ---- [B] wave0 polls cohort flags (16 peers; EXACT R6 protocol) ----
    if (s > 0 && wave == 0) {
      const int* p = flags + ((((lane & 15) << 3) | wg_m) << 4);
      while (true) {
        int v = __hip_atomic_load(p, __ATOMIC_RELAXED, __HIP_MEMORY_SCOPE_AGENT);
        if (__all(v >= s)) break;
        __builtin_amdgcn_s_sleep(1);
      }
    }
    __syncthreads();

    // ---- [C] gather h tile (8 u64 agent loads / thread) + next-x prefetch ----
    {
      const unsigned char* gsrc = (const unsigned char*)(img + (size_t)(s & 1) * IMG_HALF)
                                + (size_t)(m0 + grow) * GSTRIDE + (gq << 3);
      unsigned char* const ldst = &sm[HOFF + grow * RSTRIDE + (gq << 3)];
      unsigned long long v[8];
      #pragma unroll
      for (int i = 0; i < 8; ++i)
        v[i] = __hip_atomic_load((const unsigned long long*)(gsrc + (i << 7)),
                                 __ATOMIC_RELAXED, __HIP_MEMORY_SCOPE_AGENT);
      if (tid < 128 && s + 1 < T_STEPS) {
        const int row = tid >> 2, part = tid & 3;
        const int tt = (T_STEPS - 2) - s;
        const float* ysrc = y + (((size_t)tt * BATCH + m0 + row) << 5) + (part << 3);
        xf0 = ((const float4*)ysrc)[0];
        xf1 = ((const float4*)ysrc)[1];
        if (part == 3) tpf = tin[(size_t)tt * BATCH + m0 + row];
      }
      #pragma unroll
      for (int i = 0; i < 8; ++i)
        *(unsigned long long*)(ldst + (i << 7)) = v[i];
    }
    __syncthreads();   // h + x tiles staged

    // ---- [D] gates = [h|x|0] @ Wext^T : 18 K-steps, B-frags from registers ----
    f32x4 acc0 = {0.f, 0.f, 0.f, 0.f}, acc1 = {0.f, 0.f, 0.f, 0.f};
    #pragma unroll
    for (int ks = 0; ks < 18; ++ks) {
      const int kB = (ks << 6) + kbyl;
      short8 a0 = *(const short8*)&sm[HOFF + arow * RSTRIDE + kB];
      short8 a1 = *(const short8*)&sm[HOFF + (arow + 16) * RSTRIDE + kB];
      acc0 = __builtin_amdgcn_mfma_f32_16x16x32_bf16(a0, bfr[ks], acc0, 0, 0, 0);
      acc1 = __builtin_amdgcn_mfma_f32_16x16x32_bf16(a1, bfr[ks], acc1, 0, 0, 0);
    }

    // ---- epilogue: 4-lane butterfly to gather i/f/g/o, LSTM update (R6) ----
    float vals[8];
    #pragma unroll
    for (int r = 0; r < 4; ++r) { vals[r] = acc0[r] + bias; vals[4 + r] = acc1[r] + bias; }
    float sh1[8], sh2[8], sh3[8];
    #pragma unroll
    for (int j = 0; j < 8; ++j) {
      sh1[j] = __shfl_xor(vals[j], 1);
      sh2[j] = __shfl_xor(vals[j], 2);
      sh3[j] = __shfl_xor(vals[j], 3);
    }
    float iv0, fv0, gv0, ov0, iv1, fv1, gv1, ov1;
    if (g == 0)      { iv0=vals[0]; fv0=sh1[0]; gv0=sh2[0]; ov0=sh3[0];
                       iv1=vals[1]; fv1=sh1[1]; gv1=sh2[1]; ov1=sh3[1]; }
    else if (g == 1) { iv0=sh1[2];  fv0=vals[2];gv0=sh3[2]; ov0=sh2[2];
                       iv1=sh1[3];  fv1=vals[3];gv1=sh3[3]; ov1=sh2[3]; }
    else if (g == 2) { iv0=sh2[4];  fv0=sh3[4]; gv0=vals[4];ov0=sh1[4];
                       iv1=sh2[5];  fv1=sh3[5]; gv1=vals[5];ov1=sh1[5]; }
    else             { iv0=sh3[6];  fv0=sh2[6]; gv0=sh1[6]; ov0=vals[6];
                       iv1=sh3[7];  fv1=sh2[7]; gv1=sh1[7]; ov1=vals[7]; }

    c0 = sigm(fv0) * c0 + sigm(iv0) * tanh_f(gv0);
    float h0 = sigm(ov0) * tanh_f(c0);
    c1 = sigm(fv1) * c1 + sigm(iv1) * tanh_f(gv1);
    float h1 = sigm(ov1) * tanh_f(c1);

    // ---- [E] publish h_{s+1} (agent atomics), drain via __syncthreads, flag (R6) ----
    {
      unsigned short* gnext = img + (size_t)((s + 1) & 1) * IMG_HALF;
      const int b0 = m0 + rowbase, b1 = b0 + 1;
      __hip_atomic_store(gnext + ((size_t)b0 << 9) + ug, f2bf(h0),
                         __ATOMIC_RELAXED, __HIP_MEMORY_SCOPE_AGENT);
      __hip_atomic_store(gnext + ((size_t)b1 << 9) + ug, f2bf(h1),
                         __ATOMIC_RELAXED, __HIP_MEMORY_SCOPE_AGENT);
      if (s == T_STEPS - 1) {
        hf32[((size_t)b0 << 9) + ug] = h0;
        hf32[((size_t)b1 << 9) + ug] = h1;
      }
    }
    __syncthreads();   // per-wave vmcnt(0) drain before s_barrier -> stores visible
    if (tid == 0)
      __hip_atomic_store(own_flag, s + 1, __ATOMIC_RELAXED, __HIP_MEMORY_SCOPE_AGENT);
  }
}

// out[b][o] = sum_j hf32[b][j] * W_lin[o][j] + b_lin[o]
__global__ void __launch_bounds__(64)
out_proj(const float* __restrict__ hf, const float* __restrict__ Wl,
         const float* __restrict__ bl, float* __restrict__ out)
{
  const int b = blockIdx.x, l = threadIdx.x;
  const int o = l & 31, half = l >> 5;
  const float4* hrow = (const float4*)(hf + ((size_t)b << 9) + (half << 8));
  const float4* wrow = (const float4*)(Wl + ((size_t)o << 9) + (half << 8));
  float acc = 0.f;
  #pragma unroll 8
  for (int j = 0; j < 64; ++j) {
    float4 hv = hrow[j], wv = wrow[j];
    acc += hv.x * wv.x + hv.y * wv.y + hv.z * wv.z + hv.w * wv.w;
  }
  acc += __shfl_xor(acc, 32);
  if (l < 32) out[(b << 5) + o] = acc + bl[o];
}

extern "C" void kernel_launch(void* const* d_in, const int* in_sizes, int n_in,
                              void* d_out, int out_size, void* d_ws, size_t ws_size,
                              hipStream_t stream) {
  const float* y    = (const float*)d_in[0];
  const float* tin  = (const float*)d_in[1];
  const float* Wih  = (const float*)d_in[2];
  const float* Whh  = (const float*)d_in[3];
  const float* bih  = (const float*)d_in[4];
  const float* bhh  = (const float*)d_in[5];
  const float* Wlin = (const float*)d_in[6];
  const float* blin = (const float*)d_in[7];
  float* out = (float*)d_out;

  unsigned char* ws = (unsigned char*)d_ws;
  unsigned short* img = (unsigned short*)ws;         // 2*256*512*2B = 524288
  float* hf32 = (float*)(ws + 524288);               // 256*512*4B   = 524288
  int* flags  = (int*)(ws + 1048576);                // 128*16*4B    = 8192

  hipMemsetAsync(img, 0, BATCH * GSTRIDE, stream);   // h_0 = 0 (buffer 0 only)
  hipMemsetAsync(flags, 0, 8192, stream);            // reset flags every launch

  void* args[] = { (void*)&y, (void*)&tin, (void*)&Wih, (void*)&Whh,
                   (void*)&bih, (void*)&bhh, (void*)&img, (void*)&hf32, (void*)&flags };
  hipLaunchCooperativeKernel((const void*)lstm_persist, dim3(128), dim3(512),
                             args, 0, stream);
  out_proj<<<dim3(256), dim3(64), 0, stream>>>(hf32, Wlin, blin, out);
}

// Round 11
// 1791.389 us; speedup vs baseline: 1.0862x; 1.0862x over previous
//
#include <hip/hip_runtime.h>

// EncoderLSTM: T=512 steps, B=256, Din=33 (y:32 + t:1), H=512, OUT=32.
// Persistent cooperative kernel: 256 WGs = 8 batch-groups (32 rows) x 32 unit-groups (16 units).
// K-extended GEMM per step: gates[32x64] = [h(512)|x(33)|0] @ [W_hh|W_ih|0]^T via bf16 MFMA.
// == R6 (passed, 1603us; best) byte-for-byte EXCEPT ONE delta in [E]: ==
//   h-publish packed via quad-shfl into u64 agent stores: 512x2B -> 128x8B per WG-step.
//   (lanes r=g+4u share (b0,b1); shfl_xor dist 4,8 packs units 0..3 of a row into one u64)

#define T_STEPS 512
#define BATCH   256
#define HID     512
#define RSTRIDE 1168                  // LDS row stride bytes (292 banks % 32 = 4)
#define GSTRIDE 1024                  // global h-image row stride bytes (512 units * 2B)
#define HOFF    (64 * RSTRIDE)        // W slice: 64 rows -> 74752 B
#define LDS_BYTES (96 * RSTRIDE)      // + h tile 32 rows -> 112128 B
#define IMG_HALF (BATCH * HID)        // u16 elements per h buffer (262144 B)

typedef __attribute__((ext_vector_type(8))) short short8; // 8 bf16 (4 VGPRs)
typedef __attribute__((ext_vector_type(4))) float f32x4;

__device__ __forceinline__ unsigned short f2bf(float f) { // RNE
  union { float f; unsigned u; } v; v.f = f;
  unsigned r = v.u + 0x7FFFu + ((v.u >> 16) & 1u);
  return (unsigned short)(r >> 16);
}
__device__ __forceinline__ float sigm(float x) { return 1.f / (1.f + __expf(-x)); }
__device__ __forceinline__ float tanh_f(float x) { return 1.f - 2.f / (__expf(2.f * x) + 1.f); }

__global__ void __launch_bounds__(256, 1)
lstm_persist(const float* __restrict__ y, const float* __restrict__ tin,
             const float* __restrict__ Wih, const float* __restrict__ Whh,
             const float* __restrict__ bih, const float* __restrict__ bhh,
             unsigned short* __restrict__ img,   // [2][256][512] bf16 h
             float* __restrict__ hf32,           // [256][512]
             int* __restrict__ flags)            // [256][16] (64B stride)
{
  __shared__ __align__(16) unsigned char sm[LDS_BYTES];
  const int tid  = threadIdx.x;
  const int wave = tid >> 6, lane = tid & 63;
  const int bid  = blockIdx.x;
  const int wg_m = bid & 7;            // batch-group
  const int m0   = wg_m << 5;          // batch base (32 rows)
  const int u0   = (bid >> 3) << 4;    // unit base (16 units)

  // ---- stage W_ext slice into LDS (once): local row c = unit*4 + gate ----
  {
    const int c = tid >> 2, part = tid & 3;             // 64 rows x 4 parts (128 floats each)
    const int rg = ((c & 3) << 9) + u0 + (c >> 2);      // global gate-row = gate*512 + unit
    const float* whrow = Whh + (size_t)rg * HID;
    const int k0 = part << 7;                           // element base
    const float4* src = (const float4*)(whrow + k0);
    #pragma unroll
    for (int i = 0; i < 32; ++i) {
      float4 f = src[i];
      uint2 p2;
      p2.x = (unsigned)f2bf(f.x) | ((unsigned)f2bf(f.y) << 16);
      p2.y = (unsigned)f2bf(f.z) | ((unsigned)f2bf(f.w) << 16);
      *(uint2*)&sm[c * RSTRIDE + ((k0 + i * 4) << 1)] = p2;
    }
    if (part == 3) {
      const float* wirow = Wih + (size_t)rg * 33;       // x weights: elems 512..543
      for (int d = 0; d < 32; d += 2) {
        unsigned p = (unsigned)f2bf(wirow[d]) | ((unsigned)f2bf(wirow[d + 1]) << 16);
        *(unsigned*)&sm[c * RSTRIDE + 1024 + (d << 1)] = p;
      }
      *(unsigned short*)&sm[c * RSTRIDE + 1088] = f2bf(wirow[32]);  // t weight (elem 544)
      *(unsigned short*)&sm[c * RSTRIDE + 1090] = 0;
      *(unsigned*)&sm[c * RSTRIDE + 1092] = 0;
      uint4 z; z.x = z.y = z.z = z.w = 0;
      *(uint4*)&sm[c * RSTRIDE + 1096] = z;
      *(uint4*)&sm[c * RSTRIDE + 1112] = z;
      *(uint4*)&sm[c * RSTRIDE + 1128] = z;
      *(uint4*)&sm[c * RSTRIDE + 1144] = z;
    }
  }
  // zero h-tile K-pad (bytes 1104..1151; 1088..1103 rewritten each step) — once
  if (tid < 128) {
    int row = tid >> 2, i = tid & 3;
    if (i < 3) {
      uint4 z; z.x = z.y = z.z = z.w = 0;
      *(uint4*)&sm[HOFF + row * RSTRIDE + 1104 + i * 16] = z;
    }
  }

  // per-lane constants (R2-verified geometry)
  const int cl   = (wave << 4) + (lane & 15);            // local output col 0..63
  const int rg_l = ((cl & 3) << 9) + u0 + (cl >> 2);
  const float bias = bih[rg_l] + bhh[rg_l];
  const int ug   = u0 + (cl >> 2);                       // global unit of this lane
  const int g    = lane & 3;                             // gate owned by this lane
  const int arow = lane & 15;
  const int kbyl = (lane >> 4) << 4;
  const int rowbase = ((g >> 1) << 4) + ((lane >> 4) << 2) + ((g & 1) << 1);
  float c0 = 0.f, c1 = 0.f;
  int* const own_flag = flags + bid * 16;
  const int hrow = tid >> 3, hl8 = tid & 7;              // h gather: 32 rows x 8 thr
  const int ulocal = (lane >> 2) & 3;                    // unit index within wave's 4 units

  __syncthreads();   // W staged

  // ---- B-fragments (weights) -> registers, once ----
  short8 bfr[18];
  #pragma unroll
  for (int ks = 0; ks < 18; ++ks)
    bfr[ks] = *(const short8*)&sm[cl * RSTRIDE + (ks << 6) + kbyl];

  // ---- x prefetch for step 0 ----
  float4 xf0 = {0,0,0,0}, xf1 = {0,0,0,0}; float tpf = 0.f;
  if (tid < 128) {
    const int row = tid >> 2, part = tid & 3;
    const float* ysrc = y + (((size_t)(T_STEPS - 1) * BATCH + m0 + row) << 5) + (part << 3);
    xf0 = ((const float4*)ysrc)[0];
    xf1 = ((const float4*)ysrc)[1];
    if (part == 3) tpf = tin[(size_t)(T_STEPS - 1) * BATCH + m0 + row];
  }

  for (int s = 0; s < T_STEPS; ++s) {
    // ---- [A] x tile from prefetch regs -> LDS (elems 512..544) ----
    if (tid < 128) {
      const int row = tid >> 2, part = tid & 3;
      uint4 p;
      p.x = (unsigned)f2bf(xf0.x) | ((unsigned)f2bf(xf0.y) << 16);
      p.y = (unsigned)f2bf(xf0.z) | ((unsigned)f2bf(xf0.w) << 16);
      p.z = (unsigned)f2bf(xf1.x) | ((unsigned)f2bf(xf1.y) << 16);
      p.w = (unsigned)f2bf(xf1.z) | ((unsigned)f2bf(xf1.w) << 16);
      *(uint4*)&sm[HOFF + row * RSTRIDE + 1024 + (part << 4)] = p;
      if (part == 3) {
        uint4 tz; tz.x = (unsigned)f2bf(tpf); tz.y = tz.z = tz.w = 0;
        *(uint4*)&sm[HOFF + row * RSTRIDE + 1088] = tz;   // t + zeros (elems 544..551)
      }
    }
    // ---- [B] wave0 polls cohort flags (EXACT R6 protocol) ----
    if (s > 0 && wave == 0) {
      const int* p = flags + ((((lane & 31) << 3) | wg_m) << 4);
      while (true) {
        int v = __hip_atomic_load(p, __ATOMIC_RELAXED, __HIP_MEMORY_SCOPE_AGENT);
        if (__all(v >= s)) break;
        __builtin_amdgcn_s_sleep(1);
      }
    }
    __syncthreads();

    // ---- [C] gather h tile (16 u64 agent loads / thread) + next-x prefetch (R6) ----
    {
      const unsigned char* gsrc = (const unsigned char*)(img + (size_t)(s & 1) * IMG_HALF)
                                + (size_t)(m0 + hrow) * GSTRIDE + (hl8 << 3);
      unsigned char* const ldst = &sm[HOFF + hrow * RSTRIDE + (hl8 << 3)];
      unsigned long long v[16];
      #pragma unroll
      for (int i = 0; i < 16; ++i)
        v[i] = __hip_atomic_load((const unsigned long long*)(gsrc + (i << 6)),
                                 __ATOMIC_RELAXED, __HIP_MEMORY_SCOPE_AGENT);
      if (tid < 128 && s + 1 < T_STEPS) {
        const int row = tid >> 2, part = tid & 3;
        const int tt = (T_STEPS - 2) - s;
        const float* ysrc = y + (((size_t)tt * BATCH + m0 + row) << 5) + (part << 3);
        xf0 = ((const float4*)ysrc)[0];
        xf1 = ((const float4*)ysrc)[1];
        if (part == 3) tpf = tin[(size_t)tt * BATCH + m0 + row];
      }
      #pragma unroll
      for (int i = 0; i < 16; ++i)
        *(unsigned long long*)(ldst + (i << 6)) = v[i];
    }
    __syncthreads();   // h + x tiles staged

    // ---- [D] gates = [h|x|0] @ Wext^T : 18 K-steps, B-frags from registers ----
    f32x4 acc0 = {0.f, 0.f, 0.f, 0.f}, acc1 = {0.f, 0.f, 0.f, 0.f};
    #pragma unroll
    for (int ks = 0; ks < 18; ++ks) {
      const int kB = (ks << 6) + kbyl;
      short8 a0 = *(const short8*)&sm[HOFF + arow * RSTRIDE + kB];
      short8 a1 = *(const short8*)&sm[HOFF + (arow + 16) * RSTRIDE + kB];
      acc0 = __builtin_amdgcn_mfma_f32_16x16x32_bf16(a0, bfr[ks], acc0, 0, 0, 0);
      acc1 = __builtin_amdgcn_mfma_f32_16x16x32_bf16(a1, bfr[ks], acc1, 0, 0, 0);
    }

    // ---- epilogue: 4-lane butterfly to gather i/f/g/o, LSTM update (R6) ----
    float vals[8];
    #pragma unroll
    for (int r = 0; r < 4; ++r) { vals[r] = acc0[r] + bias; vals[4 + r] = acc1[r] + bias; }
    float sh1[8], sh2[8], sh3[8];
    #pragma unroll
    for (int j = 0; j < 8; ++j) {
      sh1[j] = __shfl_xor(vals[j], 1);
      sh2[j] = __shfl_xor(vals[j], 2);
      sh3[j] = __shfl_xor(vals[j], 3);
    }
    float iv0, fv0, gv0, ov0, iv1, fv1, gv1, ov1;
    if (g == 0)      { iv0=vals[0]; fv0=sh1[0]; gv0=sh2[0]; ov0=sh3[0];
                       iv1=vals[1]; fv1=sh1[1]; gv1=sh2[1]; ov1=sh3[1]; }
    else if (g == 1) { iv0=sh1[2];  fv0=vals[2];gv0=sh3[2]; ov0=sh2[2];
                       iv1=sh1[3];  fv1=vals[3];gv1=sh3[3]; ov1=sh2[3]; }
    else if (g == 2) { iv0=sh2[4];  fv0=sh3[4]; gv0=vals[4];ov0=sh1[4];
                       iv1=sh2[5];  fv1=sh3[5]; gv1=vals[5];ov1=sh1[5]; }
    else             { iv0=sh3[6];  fv0=sh2[6]; gv0=sh1[6]; ov0=vals[6];
                       iv1=sh3[7];  fv1=sh2[7]; gv1=sh1[7]; ov1=vals[7]; }

    c0 = sigm(fv0) * c0 + sigm(iv0) * tanh_f(gv0);
    float h0 = sigm(ov0) * tanh_f(c0);
    c1 = sigm(fv1) * c1 + sigm(iv1) * tanh_f(gv1);
    float h1 = sigm(ov1) * tanh_f(c1);

    // ---- [E] publish h_{s+1}: quad-shfl pack -> u64 agent stores (THE R11 delta) ----
    {
      // lanes r = g + 4u (fixed g, q=lane>>4) share rows (b0,b1) and span units u=0..3
      unsigned a0p = (unsigned)f2bf(h0);
      unsigned a1p = (unsigned)f2bf(h1);
      unsigned t0 = __shfl_xor(a0p, 4);
      unsigned t1 = __shfl_xor(a1p, 4);
      unsigned p0 = (ulocal & 1) == 0 ? (a0p | (t0 << 16)) : (t0 | (a0p << 16));
      unsigned p1 = (ulocal & 1) == 0 ? (a1p | (t1 << 16)) : (t1 | (a1p << 16));
      unsigned q0 = __shfl_xor(p0, 8);
      unsigned q1 = __shfl_xor(p1, 8);
      unsigned long long w0 = (ulocal & 2) == 0
        ? ((unsigned long long)p0 | ((unsigned long long)q0 << 32))
        : ((unsigned long long)q0 | ((unsigned long long)p0 << 32));
      unsigned long long w1 = (ulocal & 2) == 0
        ? ((unsigned long long)p1 | ((unsigned long long)q1 << 32))
        : ((unsigned long long)q1 | ((unsigned long long)p1 << 32));
      unsigned short* gnext = img + (size_t)((s + 1) & 1) * IMG_HALF;
      const int b0 = m0 + rowbase, b1 = b0 + 1;
      const int ucol = u0 + (wave << 2);               // first of the wave's 4 units
      if (ulocal == 0) {
        __hip_atomic_store((unsigned long long*)(gnext + ((size_t)b0 << 9) + ucol), w0,
                           __ATOMIC_RELAXED, __HIP_MEMORY_SCOPE_AGENT);
        __hip_atomic_store((unsigned long long*)(gnext + ((size_t)b1 << 9) + ucol), w1,
                           __ATOMIC_RELAXED, __HIP_MEMORY_SCOPE_AGENT);
      }
      if (s == T_STEPS - 1) {
        hf32[((size_t)b0 << 9) + ug] = h0;
        hf32[((size_t)b1 << 9) + ug] = h1;
      }
    }
    __syncthreads();   // per-wave vmcnt(0) drain before s_barrier -> stores visible
    if (tid == 0)
      __hip_atomic_store(own_flag, s + 1, __ATOMIC_RELAXED, __HIP_MEMORY_SCOPE_AGENT);
  }
}

// out[b][o] = sum_j hf32[b][j] * W_lin[o][j] + b_lin[o]
__global__ void __launch_bounds__(64)
out_proj(const float* __restrict__ hf, const float* __restrict__ Wl,
         const float* __restrict__ bl, float* __restrict__ out)
{
  const int b = blockIdx.x, l = threadIdx.x;
  const int o = l & 31, half = l >> 5;
  const float4* hrow = (const float4*)(hf + ((size_t)b << 9) + (half << 8));
  const float4* wrow = (const float4*)(Wl + ((size_t)o << 9) + (half << 8));
  float acc = 0.f;
  #pragma unroll 8
  for (int j = 0; j < 64; ++j) {
    float4 hv = hrow[j], wv = wrow[j];
    acc += hv.x * wv.x + hv.y * wv.y + hv.z * wv.z + hv.w * wv.w;
  }
  acc += __shfl_xor(acc, 32);
  if (l < 32) out[(b << 5) + o] = acc + bl[o];
}

extern "C" void kernel_launch(void* const* d_in, const int* in_sizes, int n_in,
                              void* d_out, int out_size, void* d_ws, size_t ws_size,
                              hipStream_t stream) {
  const float* y    = (const float*)d_in[0];
  const float* tin  = (const float*)d_in[1];
  const float* Wih  = (const float*)d_in[2];
  const float* Whh  = (const float*)d_in[3];
  const float* bih  = (const float*)d_in[4];
  const float* bhh  = (const float*)d_in[5];
  const float* Wlin = (const float*)d_in[6];
  const float* blin = (const float*)d_in[7];
  float* out = (float*)d_out;

  unsigned char* ws = (unsigned char*)d_ws;
  unsigned short* img = (unsigned short*)ws;         // 2*256*512*2B = 524288
  float* hf32 = (float*)(ws + 524288);               // 256*512*4B   = 524288
  int* flags  = (int*)(ws + 1048576);                // 256*16*4B    = 16384

  hipMemsetAsync(img, 0, BATCH * GSTRIDE, stream);   // h_0 = 0 (buffer 0 only)
  hipMemsetAsync(flags, 0, 16384, stream);           // reset flags every launch

  void* args[] = { (void*)&y, (void*)&tin, (void*)&Wih, (void*)&Whh,
                   (void*)&bih, (void*)&bhh, (void*)&img, (void*)&hf32, (void*)&flags };
  hipLaunchCooperativeKernel((const void*)lstm_persist, dim3(256), dim3(256),
                             args, 0, stream);
  out_proj<<<dim3(256), dim3(64), 0, stream>>>(hf32, Wlin, blin, out);
}

// Round 13
// 1581.459 us; speedup vs baseline: 1.2304x; 1.1327x over previous
//
#include <hip/hip_runtime.h>

// EncoderLSTM: T=512 steps, B=256, Din=33 (y:32 + t:1), H=512, OUT=32.
// Persistent cooperative kernel: 256 WGs = 8 batch-groups (32 rows) x 32 unit-groups (16 units).
// K-extended GEMM per step: gates[32x64] = [h(512)|x(33)|0] @ [W_hh|W_ih|0]^T via bf16 MFMA.
// == FINAL: R6 restored verbatim (best measured: 1603us, absmax 4.9e-4). ==
// Campaign evidence R7-R12: every poll/flag/write-shape/WG-shape variation regressed;
// step time is dominated by the structural IF round-trip chain of the cross-XCD h exchange
// (publish drain -> flag -> poll -> gather), which any G16-correct design must pay.

#define T_STEPS 512
#define BATCH   256
#define HID     512
#define RSTRIDE 1168                  // LDS row stride bytes (292 banks % 32 = 4)
#define GSTRIDE 1024                  // global h-image row stride bytes (512 units * 2B)
#define HOFF    (64 * RSTRIDE)        // W slice: 64 rows -> 74752 B
#define LDS_BYTES (96 * RSTRIDE)      // + h tile 32 rows -> 112128 B
#define IMG_HALF (BATCH * HID)        // u16 elements per h buffer (262144 B)

typedef __attribute__((ext_vector_type(8))) short short8; // 8 bf16 (4 VGPRs)
typedef __attribute__((ext_vector_type(4))) float f32x4;

__device__ __forceinline__ unsigned short f2bf(float f) { // RNE
  union { float f; unsigned u; } v; v.f = f;
  unsigned r = v.u + 0x7FFFu + ((v.u >> 16) & 1u);
  return (unsigned short)(r >> 16);
}
__device__ __forceinline__ float sigm(float x) { return 1.f / (1.f + __expf(-x)); }
__device__ __forceinline__ float tanh_f(float x) { return 1.f - 2.f / (__expf(2.f * x) + 1.f); }

__global__ void __launch_bounds__(256, 1)
lstm_persist(const float* __restrict__ y, const float* __restrict__ tin,
             const float* __restrict__ Wih, const float* __restrict__ Whh,
             const float* __restrict__ bih, const float* __restrict__ bhh,
             unsigned short* __restrict__ img,   // [2][256][512] bf16 h
             float* __restrict__ hf32,           // [256][512]
             int* __restrict__ flags)            // [256][16] (64B stride)
{
  __shared__ __align__(16) unsigned char sm[LDS_BYTES];
  const int tid  = threadIdx.x;
  const int wave = tid >> 6, lane = tid & 63;
  const int bid  = blockIdx.x;
  const int wg_m = bid & 7;            // batch-group
  const int m0   = wg_m << 5;          // batch base (32 rows)
  const int u0   = (bid >> 3) << 4;    // unit base (16 units)

  // ---- stage W_ext slice into LDS (once): local row c = unit*4 + gate ----
  {
    const int c = tid >> 2, part = tid & 3;             // 64 rows x 4 parts (128 floats each)
    const int rg = ((c & 3) << 9) + u0 + (c >> 2);      // global gate-row = gate*512 + unit
    const float* whrow = Whh + (size_t)rg * HID;
    const int k0 = part << 7;                           // element base
    const float4* src = (const float4*)(whrow + k0);
    #pragma unroll
    for (int i = 0; i < 32; ++i) {
      float4 f = src[i];
      uint2 p2;
      p2.x = (unsigned)f2bf(f.x) | ((unsigned)f2bf(f.y) << 16);
      p2.y = (unsigned)f2bf(f.z) | ((unsigned)f2bf(f.w) << 16);
      *(uint2*)&sm[c * RSTRIDE + ((k0 + i * 4) << 1)] = p2;
    }
    if (part == 3) {
      const float* wirow = Wih + (size_t)rg * 33;       // x weights: elems 512..543
      for (int d = 0; d < 32; d += 2) {
        unsigned p = (unsigned)f2bf(wirow[d]) | ((unsigned)f2bf(wirow[d + 1]) << 16);
        *(unsigned*)&sm[c * RSTRIDE + 1024 + (d << 1)] = p;
      }
      *(unsigned short*)&sm[c * RSTRIDE + 1088] = f2bf(wirow[32]);  // t weight (elem 544)
      *(unsigned short*)&sm[c * RSTRIDE + 1090] = 0;
      *(unsigned*)&sm[c * RSTRIDE + 1092] = 0;
      uint4 z; z.x = z.y = z.z = z.w = 0;
      *(uint4*)&sm[c * RSTRIDE + 1096] = z;
      *(uint4*)&sm[c * RSTRIDE + 1112] = z;
      *(uint4*)&sm[c * RSTRIDE + 1128] = z;
      *(uint4*)&sm[c * RSTRIDE + 1144] = z;
    }
  }
  // zero h-tile K-pad (bytes 1104..1151; 1088..1103 rewritten each step) — once
  if (tid < 128) {
    int row = tid >> 2, i = tid & 3;
    if (i < 3) {
      uint4 z; z.x = z.y = z.z = z.w = 0;
      *(uint4*)&sm[HOFF + row * RSTRIDE + 1104 + i * 16] = z;
    }
  }

  // per-lane constants (R2-verified geometry)
  const int cl   = (wave << 4) + (lane & 15);            // local output col 0..63
  const int rg_l = ((cl & 3) << 9) + u0 + (cl >> 2);
  const float bias = bih[rg_l] + bhh[rg_l];
  const int ug   = u0 + (cl >> 2);                       // global unit of this lane
  const int g    = lane & 3;                             // gate owned by this lane
  const int arow = lane & 15;
  const int kbyl = (lane >> 4) << 4;
  const int rowbase = ((g >> 1) << 4) + ((lane >> 4) << 2) + ((g & 1) << 1);
  float c0 = 0.f, c1 = 0.f;
  int* const own_flag = flags + bid * 16;
  const int hrow = tid >> 3, hl8 = tid & 7;              // h gather: 32 rows x 8 thr

  __syncthreads();   // W staged

  // ---- B-fragments (weights) -> registers, once ----
  short8 bfr[18];
  #pragma unroll
  for (int ks = 0; ks < 18; ++ks)
    bfr[ks] = *(const short8*)&sm[cl * RSTRIDE + (ks << 6) + kbyl];

  // ---- x prefetch for step 0 ----
  float4 xf0 = {0,0,0,0}, xf1 = {0,0,0,0}; float tpf = 0.f;
  if (tid < 128) {
    const int row = tid >> 2, part = tid & 3;
    const float* ysrc = y + (((size_t)(T_STEPS - 1) * BATCH + m0 + row) << 5) + (part << 3);
    xf0 = ((const float4*)ysrc)[0];
    xf1 = ((const float4*)ysrc)[1];
    if (part == 3) tpf = tin[(size_t)(T_STEPS - 1) * BATCH + m0 + row];
  }

  for (int s = 0; s < T_STEPS; ++s) {
    // ---- [A] x tile from prefetch regs -> LDS (elems 512..544) ----
    if (tid < 128) {
      const int row = tid >> 2, part = tid & 3;
      uint4 p;
      p.x = (unsigned)f2bf(xf0.x) | ((unsigned)f2bf(xf0.y) << 16);
      p.y = (unsigned)f2bf(xf0.z) | ((unsigned)f2bf(xf0.w) << 16);
      p.z = (unsigned)f2bf(xf1.x) | ((unsigned)f2bf(xf1.y) << 16);
      p.w = (unsigned)f2bf(xf1.z) | ((unsigned)f2bf(xf1.w) << 16);
      *(uint4*)&sm[HOFF + row * RSTRIDE + 1024 + (part << 4)] = p;
      if (part == 3) {
        uint4 tz; tz.x = (unsigned)f2bf(tpf); tz.y = tz.z = tz.w = 0;
        *(uint4*)&sm[HOFF + row * RSTRIDE + 1088] = tz;   // t + zeros (elems 544..551)
      }
    }
    // ---- [B] wave0 polls cohort flags ----
    if (s > 0 && wave == 0) {
      const int* p = flags + ((((lane & 31) << 3) | wg_m) << 4);
      while (true) {
        int v = __hip_atomic_load(p, __ATOMIC_RELAXED, __HIP_MEMORY_SCOPE_AGENT);
        if (__all(v >= s)) break;
        __builtin_amdgcn_s_sleep(1);
      }
    }
    __syncthreads();

    // ---- [C] gather h tile (16 u64 agent loads / thread) + next-x prefetch ----
    {
      const unsigned char* gsrc = (const unsigned char*)(img + (size_t)(s & 1) * IMG_HALF)
                                + (size_t)(m0 + hrow) * GSTRIDE + (hl8 << 3);
      unsigned char* const ldst = &sm[HOFF + hrow * RSTRIDE + (hl8 << 3)];
      unsigned long long v[16];
      #pragma unroll
      for (int i = 0; i < 16; ++i)
        v[i] = __hip_atomic_load((const unsigned long long*)(gsrc + (i << 6)),
                                 __ATOMIC_RELAXED, __HIP_MEMORY_SCOPE_AGENT);
      #pragma unroll
      for (int i = 0; i < 16; ++i)
        *(unsigned long long*)(ldst + (i << 6)) = v[i];
    }
    if (tid < 128 && s + 1 < T_STEPS) {
      const int row = tid >> 2, part = tid & 3;
      const int tt = (T_STEPS - 2) - s;
      const float* ysrc = y + (((size_t)tt * BATCH + m0 + row) << 5) + (part << 3);
      xf0 = ((const float4*)ysrc)[0];
      xf1 = ((const float4*)ysrc)[1];
      if (part == 3) tpf = tin[(size_t)tt * BATCH + m0 + row];
    }
    __syncthreads();

    // ---- [D] gates = [h|x|0] @ Wext^T : 18 K-steps, B-frags from registers ----
    f32x4 acc0 = {0.f, 0.f, 0.f, 0.f}, acc1 = {0.f, 0.f, 0.f, 0.f};
    #pragma unroll
    for (int ks = 0; ks < 18; ++ks) {
      const int kB = (ks << 6) + kbyl;
      short8 a0 = *(const short8*)&sm[HOFF + arow * RSTRIDE + kB];
      short8 a1 = *(const short8*)&sm[HOFF + (arow + 16) * RSTRIDE + kB];
      acc0 = __builtin_amdgcn_mfma_f32_16x16x32_bf16(a0, bfr[ks], acc0, 0, 0, 0);
      acc1 = __builtin_amdgcn_mfma_f32_16x16x32_bf16(a1, bfr[ks], acc1, 0, 0, 0);
    }

    // ---- epilogue: 4-lane butterfly to gather i/f/g/o, LSTM update ----
    float vals[8];
    #pragma unroll
    for (int r = 0; r < 4; ++r) { vals[r] = acc0[r] + bias; vals[4 + r] = acc1[r] + bias; }
    float sh1[8], sh2[8], sh3[8];
    #pragma unroll
    for (int j = 0; j < 8; ++j) {
      sh1[j] = __shfl_xor(vals[j], 1);
      sh2[j] = __shfl_xor(vals[j], 2);
      sh3[j] = __shfl_xor(vals[j], 3);
    }
    float iv0, fv0, gv0, ov0, iv1, fv1, gv1, ov1;
    if (g == 0)      { iv0=vals[0]; fv0=sh1[0]; gv0=sh2[0]; ov0=sh3[0];
                       iv1=vals[1]; fv1=sh1[1]; gv1=sh2[1]; ov1=sh3[1]; }
    else if (g == 1) { iv0=sh1[2];  fv0=vals[2];gv0=sh3[2]; ov0=sh2[2];
                       iv1=sh1[3];  fv1=vals[3];gv1=sh3[3]; ov1=sh2[3]; }
    else if (g == 2) { iv0=sh2[4];  fv0=sh3[4]; gv0=vals[4];ov0=sh1[4];
                       iv1=sh2[5];  fv1=sh3[5]; gv1=vals[5];ov1=sh1[5]; }
    else             { iv0=sh3[6];  fv0=sh2[6]; gv0=sh1[6]; ov0=vals[6];
                       iv1=sh3[7];  fv1=sh2[7]; gv1=sh1[7]; ov1=vals[7]; }

    c0 = sigm(fv0) * c0 + sigm(iv0) * tanh_f(gv0);
    float h0 = sigm(ov0) * tanh_f(c0);
    c1 = sigm(fv1) * c1 + sigm(iv1) * tanh_f(gv1);
    float h1 = sigm(ov1) * tanh_f(c1);

    // ---- [E] publish h_{s+1} (agent atomics), drain via __syncthreads, flag ----
    {
      unsigned short* gnext = img + (size_t)((s + 1) & 1) * IMG_HALF;
      const int b0 = m0 + rowbase, b1 = b0 + 1;
      __hip_atomic_store(gnext + ((size_t)b0 << 9) + ug, f2bf(h0),
                         __ATOMIC_RELAXED, __HIP_MEMORY_SCOPE_AGENT);
      __hip_atomic_store(gnext + ((size_t)b1 << 9) + ug, f2bf(h1),
                         __ATOMIC_RELAXED, __HIP_MEMORY_SCOPE_AGENT);
      if (s == T_STEPS - 1) {
        hf32[((size_t)b0 << 9) + ug] = h0;
        hf32[((size_t)b1 << 9) + ug] = h1;
      }
    }
    __syncthreads();   // per-wave vmcnt(0) drain before s_barrier -> stores visible
    if (tid == 0)
      __hip_atomic_store(own_flag, s + 1, __ATOMIC_RELAXED, __HIP_MEMORY_SCOPE_AGENT);
  }
}

// out[b][o] = sum_j hf32[b][j] * W_lin[o][j] + b_lin[o]
__global__ void __launch_bounds__(64)
out_proj(const float* __restrict__ hf, const float* __restrict__ Wl,
         const float* __restrict__ bl, float* __restrict__ out)
{
  const int b = blockIdx.x, l = threadIdx.x;
  const int o = l & 31, half = l >> 5;
  const float4* hrow = (const float4*)(hf + ((size_t)b << 9) + (half << 8));
  const float4* wrow = (const float4*)(Wl + ((size_t)o << 9) + (half << 8));
  float acc = 0.f;
  #pragma unroll 8
  for (int j = 0; j < 64; ++j) {
    float4 hv = hrow[j], wv = wrow[j];
    acc += hv.x * wv.x + hv.y * wv.y + hv.z * wv.z + hv.w * wv.w;
  }
  acc += __shfl_xor(acc, 32);
  if (l < 32) out[(b << 5) + o] = acc + bl[o];
}

extern "C" void kernel_launch(void* const* d_in, const int* in_sizes, int n_in,
                              void* d_out, int out_size, void* d_ws, size_t ws_size,
                              hipStream_t stream) {
  const float* y    = (const float*)d_in[0];
  const float* tin  = (const float*)d_in[1];
  const float* Wih  = (const float*)d_in[2];
  const float* Whh  = (const float*)d_in[3];
  const float* bih  = (const float*)d_in[4];
  const float* bhh  = (const float*)d_in[5];
  const float* Wlin = (const float*)d_in[6];
  const float* blin = (const float*)d_in[7];
  float* out = (float*)d_out;

  unsigned char* ws = (unsigned char*)d_ws;
  unsigned short* img = (unsigned short*)ws;         // 2*256*512*2B = 524288
  float* hf32 = (float*)(ws + 524288);               // 256*512*4B   = 524288
  int* flags  = (int*)(ws + 1048576);                // 256*16*4B    = 16384

  hipMemsetAsync(img, 0, BATCH * GSTRIDE, stream);   // h_0 = 0 (buffer 0 only)
  hipMemsetAsync(flags, 0, 16384, stream);           // reset flags every launch

  void* args[] = { (void*)&y, (void*)&tin, (void*)&Wih, (void*)&Whh,
                   (void*)&bih, (void*)&bhh, (void*)&img, (void*)&hf32, (void*)&flags };
  hipLaunchCooperativeKernel((const void*)lstm_persist, dim3(256), dim3(256),
                             args, 0, stream);
  out_proj<<<dim3(256), dim3(64), 0, stream>>>(hf32, Wlin, blin, out);
}